// Round 1
// baseline (728.003 us; speedup 1.0000x reference)
//
#include <hip/hip_runtime.h>
#include <math.h>

#define HW 4096   // H*W = 64*64
// B=4, C=64, H=W=64. L = 4096.
// Outputs: S [B,1,H,W] = 16384 floats, then T [B,C,H,W] = 1048576 floats.

// ---------------- pixel squared norms (per-pixel, over C) ----------------
__global__ void pixnorm_kernel(const float* __restrict__ Q, const float* __restrict__ K,
                               float* __restrict__ pix2q, float* __restrict__ pix2k) {
    int idx = blockIdx.x * 256 + threadIdx.x;   // b*4096 + p
    int b = idx >> 12, p = idx & 4095;
    const float* qb = Q + (size_t)b * 64 * HW + p;
    const float* kb = K + (size_t)b * 64 * HW + p;
    float sq = 0.f, sk = 0.f;
#pragma unroll 8
    for (int c = 0; c < 64; ++c) {
        float a = qb[(size_t)c * HW];
        float d = kb[(size_t)c * HW];
        sq = fmaf(a, a, sq);
        sk = fmaf(d, d, sk);
    }
    pix2q[idx] = sq;
    pix2k[idx] = sk;
}

// ---------------- patch reciprocal norms: 1/max(sqrt(3x3 box sum), 1e-12) ----
__global__ void patchnorm_kernel(const float* __restrict__ pix2q, const float* __restrict__ pix2k,
                                 float* __restrict__ rnq, float* __restrict__ rnk) {
    int idx = blockIdx.x * 256 + threadIdx.x;   // b*4096 + p
    int b = idx >> 12, p = idx & 4095;
    int py = p >> 6, px = p & 63;
    float sq = 0.f, sk = 0.f;
    for (int dy = -1; dy <= 1; ++dy)
        for (int dx = -1; dx <= 1; ++dx) {
            int yy = py + dy, xx = px + dx;
            if ((unsigned)yy < 64u && (unsigned)xx < 64u) {
                int o = (b << 12) + (yy << 6) + xx;
                sq += pix2q[o];
                sk += pix2k[o];
            }
        }
    rnq[idx] = 1.f / fmaxf(sqrtf(sq), 1e-12f);
    rnk[idx] = 1.f / fmaxf(sqrtf(sk), 1e-12f);
}

// ---------------- fp32 GEMM: D[lq][k] = sum_c Q[c][qbase+lq] * K[c][k] --------
// M = (cs+2)*64 local q rows (1-row halo each side), N = 4096 k, K = 64 c.
__global__ __launch_bounds__(256, 2)
void gemm_kernel(const float* __restrict__ Q, const float* __restrict__ K,
                 float* __restrict__ D, int b, int qbase) {
    __shared__ __align__(16) float As[64][128];
    __shared__ __align__(16) float Bs[64][128];
    const int tid = threadIdx.x;
    const int k0 = blockIdx.x * 128;
    const int q0 = blockIdx.y * 128;
    const float* Qb = Q + (size_t)b * 64 * HW;
    const float* Kb = K + (size_t)b * 64 * HW;
    for (int i = tid; i < 64 * 128; i += 256) {
        int c = i >> 7, col = i & 127;
        int gq = qbase + q0 + col;
        As[c][col] = ((unsigned)gq < (unsigned)HW) ? Qb[(size_t)c * HW + gq] : 0.f;
        Bs[c][col] = Kb[(size_t)c * HW + k0 + col];
    }
    __syncthreads();
    const int tx = tid & 15, ty = tid >> 4;
    float acc[8][8];
#pragma unroll
    for (int i = 0; i < 8; ++i)
#pragma unroll
        for (int j = 0; j < 8; ++j) acc[i][j] = 0.f;
#pragma unroll 8
    for (int c = 0; c < 64; ++c) {
        const float4* ap = (const float4*)&As[c][ty * 8];
        const float4* bp = (const float4*)&Bs[c][tx * 8];
        float4 a0 = ap[0], a1 = ap[1];
        float4 b0 = bp[0], b1 = bp[1];
        float av[8] = {a0.x, a0.y, a0.z, a0.w, a1.x, a1.y, a1.z, a1.w};
        float bv[8] = {b0.x, b0.y, b0.z, b0.w, b1.x, b1.y, b1.z, b1.w};
#pragma unroll
        for (int i = 0; i < 8; ++i)
#pragma unroll
            for (int j = 0; j < 8; ++j) acc[i][j] = fmaf(av[i], bv[j], acc[i][j]);
    }
#pragma unroll
    for (int i = 0; i < 8; ++i) {
        int lq = q0 + ty * 8 + i;
        int gq = qbase + lq;
        if ((unsigned)gq < (unsigned)HW) {
            float* dst = D + (size_t)lq * HW + k0 + tx * 8;
            ((float4*)dst)[0] = make_float4(acc[i][0], acc[i][1], acc[i][2], acc[i][3]);
            ((float4*)dst)[1] = make_float4(acc[i][4], acc[i][5], acc[i][6], acc[i][7]);
        }
    }
}

// ---------------- reducer: per q, max_k (sum of 9 shifted D) * rnk[k] ----------
// WG: q-tile 4x8 (32 queries), k-split s covers ky rows [8s, 8s+8).
// LDS ring of 3 slabs, one per ky' row: slab[ky'][qy'l(6)][qx'l(10)][kx'(66)],
// zero-padded so the 9-term sum needs no masks.
__global__ __launch_bounds__(256, 3)
void reduce_kernel(const float* __restrict__ D, const float* __restrict__ rnkA,
                   float* __restrict__ part_val, int* __restrict__ part_arg,
                   int b, int chunk, int cs, int qrow0) {
    __shared__ float slab[3][3960];   // 60 rows * 66
    const int s = blockIdx.x;         // 0..7
    const int tl = blockIdx.y;        // 0..2*cs-1
    const int qty = chunk * (cs >> 2) + (tl >> 3);
    const int qtx = tl & 7;
    const int tid = threadIdx.x;
    const int kx = tid & 63, wq = tid >> 6;
    const int qy0 = qty * 4, qx0 = qtx * 8;

    // Precompute global-D offsets for the slab-load pattern (stage-invariant).
    int offs[16];
#pragma unroll
    for (int t = 0; t < 16; ++t) {
        int i = t * 256 + tid;
        int off = -1;
        if (i < 3960) {
            int rowi = i / 66;
            int kxp = i - rowi * 66;
            int qyl = rowi / 10;
            int qxl = rowi - qyl * 10;
            int qy = qy0 - 1 + qyl;
            int qx = qx0 - 1 + qxl;
            int kk = kxp - 1;
            if ((unsigned)qy < 64u && (unsigned)qx < 64u && (unsigned)kk < 64u)
                off = ((qy - qrow0) * 64 + qx) * HW + kk;
        }
        offs[t] = off;
    }

    auto load_slab = [&](int slot, int rp) {
        float* sp = slab[slot];
        if ((unsigned)rp < 64u) {
            const float* dp = D + rp * 64;
#pragma unroll
            for (int t = 0; t < 16; ++t) {
                int i = t * 256 + tid;
                if (i < 3960) sp[i] = (offs[t] >= 0) ? dp[offs[t]] : 0.f;
            }
        } else {
#pragma unroll
            for (int t = 0; t < 16; ++t) {
                int i = t * 256 + tid;
                if (i < 3960) sp[i] = 0.f;
            }
        }
    };

    const int r0 = s * 8;
    float best[8];
    int barg[8];
#pragma unroll
    for (int j = 0; j < 8; ++j) { best[j] = -INFINITY; barg[j] = 0; }

    load_slab((r0 + 0) % 3, r0 - 1);   // slot(ky') = (ky'+1)%3
    load_slab((r0 + 1) % 3, r0);

    for (int gr = r0; gr < r0 + 8; ++gr) {
        load_slab((gr + 2) % 3, gr + 1);
        __syncthreads();
        float rk = rnkA[(b << 12) + (gr << 6) + kx];
        const float* sb0 = &slab[(gr + 0) % 3][(wq + 0) * 660 + kx];
        const float* sb1 = &slab[(gr + 1) % 3][(wq + 1) * 660 + kx];
        const float* sb2 = &slab[(gr + 2) % 3][(wq + 2) * 660 + kx];
        int kg = (gr << 6) + kx;
#pragma unroll
        for (int j = 0; j < 8; ++j) {
            const int o = (j + 1) * 66 + 1;   // literal after unroll -> imm ds offsets
            float v = sb0[o - 67] + sb0[o] + sb0[o + 67]
                    + sb1[o - 67] + sb1[o] + sb1[o + 67]
                    + sb2[o - 67] + sb2[o] + sb2[o + 67];
            v *= rk;
            if (v > best[j]) { best[j] = v; barg[j] = kg; }   // strict >: first max wins
        }
        __syncthreads();
    }

    const int tg = qty * 8 + qtx;
#pragma unroll
    for (int j = 0; j < 8; ++j) {
        float v = best[j];
        int a = barg[j];
#pragma unroll
        for (int m = 32; m >= 1; m >>= 1) {
            float ov = __shfl_xor(v, m, 64);
            int oa = __shfl_xor(a, m, 64);
            if (ov > v || (ov == v && oa < a)) { v = ov; a = oa; }
        }
        if (kx == 0) {
            int f = wq * 8 + j;
            int pi = (((b << 7) + tg) * 8 + s) * 32 + f;
            part_val[pi] = v;
            part_arg[pi] = a;
        }
    }
}

// ---------------- combine k-split partials, apply 1/||Q patch||, emit S + arg --
__global__ void combine_kernel(const float* __restrict__ part_val, const int* __restrict__ part_arg,
                               const float* __restrict__ rnqA,
                               float* __restrict__ S_out, int* __restrict__ arg_out) {
    int idx = blockIdx.x * 256 + threadIdx.x;   // b*4096 + q
    int b = idx >> 12, q = idx & 4095;
    int qy = q >> 6, qx = q & 63;
    int tg = ((qy >> 2) << 3) + (qx >> 3);
    int f = ((qy & 3) << 3) + (qx & 7);
    const float* pv = part_val + (size_t)(((b << 7) + tg) * 8) * 32 + f;
    const int* pa = part_arg + (size_t)(((b << 7) + tg) * 8) * 32 + f;
    float bv = -INFINITY;
    int ba = 0;
#pragma unroll
    for (int s = 0; s < 8; ++s) {   // ascending s = ascending k ranges: first max wins
        float v = pv[s * 32];
        int a = pa[s * 32];
        if (v > bv) { bv = v; ba = a; }
    }
    S_out[idx] = bv * rnqA[idx];
    arg_out[idx] = ba;
}

// ---------------- gather + fold: T[c,y,x] = (1/9) sum_{dy,dx} Vzp[c, a(q)+d], q=(y-dy,x-dx)
__global__ __launch_bounds__(256)
void gather_kernel(const float* __restrict__ V, const int* __restrict__ arg,
                   float* __restrict__ T_out) {
    int y = blockIdx.x, b = blockIdx.y;
    int tid = threadIdx.x;
    int x = tid & 63, cq = tid >> 6;
    int off[9];
#pragma unroll
    for (int t = 0; t < 9; ++t) {
        int dy = t / 3 - 1, dx = t % 3 - 1;
        int qy = y - dy, qx = x - dx;
        int o = -1;
        if ((unsigned)qy < 64u && (unsigned)qx < 64u) {
            int a = arg[(b << 12) + (qy << 6) + qx];
            int sy = (a >> 6) + dy, sx = (a & 63) + dx;
            if ((unsigned)sy < 64u && (unsigned)sx < 64u) o = (sy << 6) + sx;
        }
        off[t] = o;
    }
    const float* Vb = V + (size_t)b * 64 * HW;
    float* Tb = T_out + (size_t)b * 64 * HW + (y << 6) + x;
    for (int ci = 0; ci < 16; ++ci) {
        int c = cq * 16 + ci;
        const float* Vc = Vb + (size_t)c * HW;
        float acc = 0.f;
#pragma unroll
        for (int t = 0; t < 9; ++t)
            acc += (off[t] >= 0) ? Vc[off[t]] : 0.f;
        Tb[(size_t)c * HW] = acc * (1.f / 9.f);
    }
}

extern "C" void kernel_launch(void* const* d_in, const int* in_sizes, int n_in,
                              void* d_out, int out_size, void* d_ws, size_t ws_size,
                              hipStream_t stream) {
    const float* V = (const float*)d_in[0];
    const float* K = (const float*)d_in[1];
    const float* Q = (const float*)d_in[2];
    float* S_out = (float*)d_out;            // 4*4096
    float* T_out = S_out + 4 * HW;           // 4*64*4096

    char* ws = (char*)d_ws;
    float* pix2q = (float*)ws;               // 16384 f
    float* pix2k = pix2q + 16384;            // 16384 f
    float* rnq = pix2k + 16384;              // 16384 f
    float* rnk = rnq + 16384;                // 16384 f
    int* argb = (int*)(rnk + 16384);         // 16384 i
    float* part_val = (float*)(argb + 16384);        // 131072 f
    int* part_arg = (int*)(part_val + 131072);       // 131072 i
    float* D = (float*)(ws + 1376256);       // (cs+2)*64*4096 f

    // q-row chunking chosen from ws_size (nc=1 needs ~70.6 MB total).
    int nc = 8;
    {
        const int cands[4] = {1, 2, 4, 8};
        for (int t = 0; t < 4; ++t) {
            int c = cands[t];
            size_t need = 1376256ull + (size_t)(64 / c + 2) * 64 * HW * 4ull;
            if (need <= ws_size) { nc = c; break; }
        }
    }
    int cs = 64 / nc;

    pixnorm_kernel<<<64, 256, 0, stream>>>(Q, K, pix2q, pix2k);
    patchnorm_kernel<<<64, 256, 0, stream>>>(pix2q, pix2k, rnq, rnk);
    for (int b = 0; b < 4; ++b) {
        for (int c = 0; c < nc; ++c) {
            int qrow0 = c * cs - 1;
            int Mtiles = (cs + 2) >> 1;   // ((cs+2)*64)/128, exact
            gemm_kernel<<<dim3(32, Mtiles), 256, 0, stream>>>(Q, K, D, b, qrow0 * 64);
            reduce_kernel<<<dim3(8, 2 * cs), 256, 0, stream>>>(D, rnk, part_val, part_arg,
                                                               b, c, cs, qrow0);
        }
    }
    combine_kernel<<<64, 256, 0, stream>>>(part_val, part_arg, rnq, S_out, argb);
    gather_kernel<<<dim3(64, 4), 256, 0, stream>>>(V, argb, T_out);
}

// Round 2
// 494.427 us; speedup vs baseline: 1.4724x; 1.4724x over previous
//
#include <hip/hip_runtime.h>
#include <math.h>

#define HW 4096   // H*W = 64*64; B=4, C=64, H=W=64, L=4096

// ---------------- pixel squared norms (per-pixel, over C) ----------------
__global__ void pixnorm_kernel(const float* __restrict__ Q, const float* __restrict__ K,
                               float* __restrict__ pix2q, float* __restrict__ pix2k) {
    int idx = blockIdx.x * 256 + threadIdx.x;   // b*4096 + p
    int b = idx >> 12, p = idx & 4095;
    const float* qb = Q + (size_t)b * 64 * HW + p;
    const float* kb = K + (size_t)b * 64 * HW + p;
    float sq = 0.f, sk = 0.f;
#pragma unroll 8
    for (int c = 0; c < 64; ++c) {
        float a = qb[(size_t)c * HW];
        float d = kb[(size_t)c * HW];
        sq = fmaf(a, a, sq);
        sk = fmaf(d, d, sk);
    }
    pix2q[idx] = sq;
    pix2k[idx] = sk;
}

// ---------------- patch reciprocal norms: 1/max(sqrt(3x3 box sum), 1e-12) ----
__global__ void patchnorm_kernel(const float* __restrict__ pix2q, const float* __restrict__ pix2k,
                                 float* __restrict__ rnq, float* __restrict__ rnk) {
    int idx = blockIdx.x * 256 + threadIdx.x;   // b*4096 + p
    int b = idx >> 12, p = idx & 4095;
    int py = p >> 6, px = p & 63;
    float sq = 0.f, sk = 0.f;
    for (int dy = -1; dy <= 1; ++dy)
        for (int dx = -1; dx <= 1; ++dx) {
            int yy = py + dy, xx = px + dx;
            if ((unsigned)yy < 64u && (unsigned)xx < 64u) {
                int o = (b << 12) + (yy << 6) + xx;
                sq += pix2q[o];
                sk += pix2k[o];
            }
        }
    rnq[idx] = 1.f / fmaxf(sqrtf(sq), 1e-12f);
    rnk[idx] = 1.f / fmaxf(sqrtf(sk), 1e-12f);
}

// ---------------- fused GEMM + x-diagonal 3-sum ------------------------------
// D[q][k] = sum_c Q[c][q]*K[c][k];  Dx[q][k] = mlo*D[q-1][k-1] + D[q][k] + mhi*D[q+1][k+1]
// (x-shifts: qx+-1 / kx+-1, zero at image edges -> masks). Tile 128q x 128k, K=64.
// Micro-tile: q = q0 + iG*64 + ty*4 + i, k = k0 + jG*64 + tx*4 + j (iG,jG in {0,1}).
// Chunked along qy: chunk covers qy rows [8c-1, 8c+9) -> 640 local rows.
__global__ __launch_bounds__(256, 2)
void gemm_dx_kernel(const float* __restrict__ Q, const float* __restrict__ K,
                    float* __restrict__ Dx, int chunk) {
    __shared__ __align__(16) float sdata[16384];   // As[64][128] | Bs[64][128]; epilogue: xch
    float* As = sdata;
    float* Bs = sdata + 8192;
    const int tid = threadIdx.x;
    const int tx = tid & 15, ty = tid >> 4;
    const int lane = tid & 63;
    const int k0 = blockIdx.x * 128;
    const int q0 = blockIdx.y * 128;
    const int b  = blockIdx.z;
    const int qbase = (chunk * 8 - 1) * 64;
    const float* Qb = Q + (size_t)b * 64 * HW;
    const float* Kb = K + (size_t)b * 64 * HW;

#pragma unroll
    for (int t = 0; t < 8; ++t) {
        int i4 = t * 256 + tid;            // 0..2047 float4 slots
        int c = i4 >> 5;
        int col = (i4 & 31) * 4;
        int gq = qbase + q0 + col;         // 4-aligned; whole float4 in/out together
        float4 av = make_float4(0.f, 0.f, 0.f, 0.f);
        if ((unsigned)gq < (unsigned)HW) av = *(const float4*)&Qb[(size_t)c * HW + gq];
        *(float4*)&As[c * 128 + col] = av;
        *(float4*)&Bs[c * 128 + col] = *(const float4*)&Kb[(size_t)c * HW + k0 + col];
    }
    __syncthreads();

    float accf[8][8];                      // [r=iG*4+i][cc=jG*4+j]
#pragma unroll
    for (int r = 0; r < 8; ++r)
#pragma unroll
        for (int cc = 0; cc < 8; ++cc) accf[r][cc] = 0.f;

#pragma unroll 8
    for (int c = 0; c < 64; ++c) {
        float4 a0 = *(const float4*)&As[c * 128 + ty * 4];
        float4 a1 = *(const float4*)&As[c * 128 + 64 + ty * 4];
        float4 b0 = *(const float4*)&Bs[c * 128 + tx * 4];
        float4 b1 = *(const float4*)&Bs[c * 128 + 64 + tx * 4];
        float av[8] = {a0.x, a0.y, a0.z, a0.w, a1.x, a1.y, a1.z, a1.w};
        float bv[8] = {b0.x, b0.y, b0.z, b0.w, b1.x, b1.y, b1.z, b1.w};
#pragma unroll
        for (int r = 0; r < 8; ++r)
#pragma unroll
            for (int cc = 0; cc < 8; ++cc) accf[r][cc] = fmaf(av[r], bv[cc], accf[r][cc]);
    }
    __syncthreads();   // As/Bs dead; reuse front of sdata as exchange buffer

    // wave-boundary row exchange: rows qx in {15,31,47} (side0) and {16,32,48} (side1), per iG
    // xch[((iG*3 + bnd)*2 + side)*132 + col], col = jG*64 + kxlocal
    float* xch = sdata;
    bool wlow  = (ty == 3 || ty == 7 || ty == 11);    // writes its i=3 rows (qx 15/31/47)
    bool whigh = (ty == 4 || ty == 8 || ty == 12);    // writes its i=0 rows (qx 16/32/48)
    if (wlow) {
        int bnd = ty >> 2;
#pragma unroll
        for (int iG = 0; iG < 2; ++iG)
#pragma unroll
            for (int jG = 0; jG < 2; ++jG)
#pragma unroll
                for (int j = 0; j < 4; ++j)
                    xch[((iG * 3 + bnd) * 2 + 0) * 132 + jG * 64 + tx * 4 + j] = accf[iG * 4 + 3][jG * 4 + j];
    }
    if (whigh) {
        int bnd = (ty >> 2) - 1;
#pragma unroll
        for (int iG = 0; iG < 2; ++iG)
#pragma unroll
            for (int jG = 0; jG < 2; ++jG)
#pragma unroll
                for (int j = 0; j < 4; ++j)
                    xch[((iG * 3 + bnd) * 2 + 1) * 132 + jG * 64 + tx * 4 + j] = accf[iG * 4][jG * 4 + j];
    }
    __syncthreads();

    // cross-thread neighbor values via in-wave shuffles (garbage lanes are masked later)
    float Lv[8][2], Rv[8][2], Uv[2][2][3], Dv[2][2][3], cUL[2][2], cDR[2][2];
#pragma unroll
    for (int m = 0; m < 7; ++m)
#pragma unroll
        for (int g = 0; g < 2; ++g) Lv[m][g] = __shfl(accf[m][g * 4 + 3], lane - 1, 64);
#pragma unroll
    for (int m = 1; m < 8; ++m)
#pragma unroll
        for (int g = 0; g < 2; ++g) Rv[m][g] = __shfl(accf[m][g * 4], lane + 1, 64);
#pragma unroll
    for (int iG = 0; iG < 2; ++iG)
#pragma unroll
        for (int g = 0; g < 2; ++g) {
#pragma unroll
            for (int m = 0; m < 3; ++m) {
                Uv[iG][g][m] = __shfl(accf[iG * 4 + 3][g * 4 + m], lane - 16, 64);
                Dv[iG][g][m] = __shfl(accf[iG * 4][g * 4 + m + 1], lane + 16, 64);
            }
            cUL[iG][g] = __shfl(accf[iG * 4 + 3][g * 4 + 3], lane - 17, 64);
            cDR[iG][g] = __shfl(accf[iG * 4][g * 4], lane + 17, 64);
        }
    if (whigh) {   // row above (qx0-1) comes from LDS, not shfl (crosses wave)
        int bnd = (ty >> 2) - 1;
#pragma unroll
        for (int iG = 0; iG < 2; ++iG)
#pragma unroll
            for (int g = 0; g < 2; ++g) {
                int base = ((iG * 3 + bnd) * 2 + 0) * 132 + g * 64 + tx * 4;
#pragma unroll
                for (int m = 0; m < 3; ++m) Uv[iG][g][m] = xch[base + m];
                cUL[iG][g] = xch[base > 0 ? base - 1 : 0];
            }
    }
    if (wlow) {    // row below (qx0+4)
        int bnd = ty >> 2;
#pragma unroll
        for (int iG = 0; iG < 2; ++iG)
#pragma unroll
            for (int g = 0; g < 2; ++g) {
                int base = ((iG * 3 + bnd) * 2 + 1) * 132 + g * 64 + tx * 4;
#pragma unroll
                for (int m = 0; m < 3; ++m) Dv[iG][g][m] = xch[base + m + 1];
                cDR[iG][g] = xch[base + 4];
            }
    }

    // assemble Dx and store
#pragma unroll
    for (int r = 0; r < 8; ++r) {
        int iG = r >> 2, i3 = r & 3;
        size_t row = (size_t)(b * 640 + q0 + iG * 64 + ty * 4 + i3);
#pragma unroll
        for (int jG = 0; jG < 2; ++jG) {
            float o[4];
#pragma unroll
            for (int j3 = 0; j3 < 4; ++j3) {
                int cc = jG * 4 + j3;
                float dm, dp;
                if (i3 > 0) dm = (j3 > 0) ? accf[r - 1][cc - 1] : Lv[r - 1][jG];
                else        dm = (j3 > 0) ? Uv[iG][jG][j3 - 1] : cUL[iG][jG];
                if (i3 < 3) dp = (j3 < 3) ? accf[r + 1][cc + 1] : Rv[r + 1][jG];
                else        dp = (j3 < 3) ? Dv[iG][jG][j3] : cDR[iG][jG];
                int qx = ty * 4 + i3, kx = tx * 4 + j3;
                float v = accf[r][cc];
                if (qx > 0 && kx > 0)   v += dm;
                if (qx < 63 && kx < 63) v += dp;
                o[j3] = v;
            }
            *(float4*)&Dx[row * HW + k0 + jG * 64 + tx * 4] = make_float4(o[0], o[1], o[2], o[3]);
        }
    }
}

// ---------------- reduce: y-diagonal 3-sum + argmax, pure-register pipeline ---
// R[(qy,qx)][(ky,kx)] = Dx[qy-1][ky-1] + Dx[qy][ky] + Dx[qy+1][ky+1] (same qx,kx)
// thread: (wq -> qx, lane -> kx); outputs qy = 8*chunk + j, j=0..7; ky split s: [8s, 8s+8)
__global__ __launch_bounds__(256, 4)
void reduce_kernel(const float* __restrict__ Dx, const float* __restrict__ rnkA,
                   float* __restrict__ part_val, int* __restrict__ part_arg, int chunk) {
    const int s = blockIdx.x;          // 0..7
    const int qxT = blockIdx.y;        // 0..15
    const int b = blockIdx.z;
    const int tid = threadIdx.x;
    const int kx = tid & 63, wq = tid >> 6;
    const int qx = qxT * 4 + wq;
    const float* base = Dx + (size_t)b * 640 * HW;

    float P0[8], P1[8], best[8];
    int barg[8];
#pragma unroll
    for (int j = 0; j < 8; ++j) { P0[j] = 0.f; P1[j] = 0.f; best[j] = -INFINITY; barg[j] = 0; }

    const int t0 = s * 8 - 1;
    for (int step = 0; step < 10; ++step) {
        int t = t0 + step;
        bool tval = (unsigned)t < 64u;
        float E[10];
#pragma unroll
        for (int lj = 0; lj < 10; ++lj) {
            int qy = 8 * chunk - 1 + lj;
            bool v = tval && (unsigned)qy < 64u;
            E[lj] = v ? base[(size_t)(lj * 64 + qx) * HW + t * 64 + kx] : 0.f;
        }
        if (step >= 2) {
            float rk = rnkA[(b << 12) + ((t - 1) << 6) + kx];   // key = (t-1, kx), always valid
            int kg = (t - 1) * 64 + kx;
#pragma unroll
            for (int j = 0; j < 8; ++j) {
                float v = (P1[j] + E[j + 2]) * rk;
                if (v > best[j]) { best[j] = v; barg[j] = kg; }   // strict >: first max wins
            }
        }
#pragma unroll
        for (int j = 0; j < 8; ++j) { P1[j] = P0[j] + E[j + 1]; P0[j] = E[j]; }
    }

#pragma unroll
    for (int j = 0; j < 8; ++j) {
        float v = best[j];
        int a = barg[j];
#pragma unroll
        for (int m = 32; m >= 1; m >>= 1) {
            float ov = __shfl_xor(v, m, 64);
            int oa = __shfl_xor(a, m, 64);
            if (ov > v || (ov == v && oa < a)) { v = ov; a = oa; }
        }
        if (kx == 0) {
            int qy = 8 * chunk + j;
            int pi = ((b << 12) + (qy << 6) + qx) * 8 + s;
            part_val[pi] = v;
            part_arg[pi] = a;
        }
    }
}

// ---------------- combine k-split partials, apply 1/||Q patch||, emit S + arg --
__global__ void combine_kernel(const float* __restrict__ part_val, const int* __restrict__ part_arg,
                               const float* __restrict__ rnqA,
                               float* __restrict__ S_out, int* __restrict__ arg_out) {
    int idx = blockIdx.x * 256 + threadIdx.x;   // b*4096 + q
    const float* pv = part_val + (size_t)idx * 8;
    const int* pa = part_arg + (size_t)idx * 8;
    float bv = -INFINITY;
    int ba = 0;
#pragma unroll
    for (int s = 0; s < 8; ++s) {   // ascending s = ascending k ranges: first max wins
        float v = pv[s];
        int a = pa[s];
        if (v > bv) { bv = v; ba = a; }
    }
    S_out[idx] = bv * rnqA[idx];
    arg_out[idx] = ba;
}

// ---------------- gather + fold: T[c,y,x] = (1/9) sum_{dy,dx} Vzp[c, a(q)+d], q=(y-dy,x-dx)
__global__ __launch_bounds__(256)
void gather_kernel(const float* __restrict__ V, const int* __restrict__ arg,
                   float* __restrict__ T_out) {
    int y = blockIdx.x, b = blockIdx.y;
    int tid = threadIdx.x;
    int x = tid & 63, cq = tid >> 6;
    int off[9];
#pragma unroll
    for (int t = 0; t < 9; ++t) {
        int dy = t / 3 - 1, dx = t % 3 - 1;
        int qy = y - dy, qx = x - dx;
        int o = -1;
        if ((unsigned)qy < 64u && (unsigned)qx < 64u) {
            int a = arg[(b << 12) + (qy << 6) + qx];
            int sy = (a >> 6) + dy, sx = (a & 63) + dx;
            if ((unsigned)sy < 64u && (unsigned)sx < 64u) o = (sy << 6) + sx;
        }
        off[t] = o;
    }
    const float* Vb = V + (size_t)b * 64 * HW;
    float* Tb = T_out + (size_t)b * 64 * HW + (y << 6) + x;
    for (int ci = 0; ci < 16; ++ci) {
        int c = cq * 16 + ci;
        const float* Vc = Vb + (size_t)c * HW;
        float acc = 0.f;
#pragma unroll
        for (int t = 0; t < 9; ++t)
            acc += (off[t] >= 0) ? Vc[off[t]] : 0.f;
        Tb[(size_t)c * HW] = acc * (1.f / 9.f);
    }
}

extern "C" void kernel_launch(void* const* d_in, const int* in_sizes, int n_in,
                              void* d_out, int out_size, void* d_ws, size_t ws_size,
                              hipStream_t stream) {
    const float* V = (const float*)d_in[0];
    const float* K = (const float*)d_in[1];
    const float* Q = (const float*)d_in[2];
    float* S_out = (float*)d_out;            // 4*4096
    float* T_out = S_out + 4 * HW;           // 4*64*4096

    char* ws = (char*)d_ws;
    float* pix2q = (float*)ws;               // 16384 f
    float* pix2k = pix2q + 16384;
    float* rnq = pix2k + 16384;
    float* rnk = rnq + 16384;
    int* argb = (int*)(rnk + 16384);
    float* part_val = (float*)(argb + 16384);        // 4*4096*8 f
    int* part_arg = (int*)(part_val + 131072);
    float* Dx = (float*)(ws + 1376256);      // 4 batches * 640 rows * 4096 f = 41.9 MB

    pixnorm_kernel<<<64, 256, 0, stream>>>(Q, K, pix2q, pix2k);
    patchnorm_kernel<<<64, 256, 0, stream>>>(pix2q, pix2k, rnq, rnk);
    for (int c = 0; c < 8; ++c) {
        gemm_dx_kernel<<<dim3(32, 5, 4), 256, 0, stream>>>(Q, K, Dx, c);
        reduce_kernel<<<dim3(8, 16, 4), 256, 0, stream>>>(Dx, rnk, part_val, part_arg, c);
    }
    combine_kernel<<<64, 256, 0, stream>>>(part_val, part_arg, rnq, S_out, argb);
    gather_kernel<<<dim3(64, 4), 256, 0, stream>>>(V, argb, T_out);
}

// Round 3
// 348.990 us; speedup vs baseline: 2.0860x; 1.4167x over previous
//
#include <hip/hip_runtime.h>
#include <math.h>

#define HW 4096   // H*W = 64*64; B=4, C=64, H=W=64, L=4096

// ---------------- pixel squared norms (per-pixel, over C) ----------------
__global__ void pixnorm_kernel(const float* __restrict__ Q, const float* __restrict__ K,
                               float* __restrict__ pix2q, float* __restrict__ pix2k) {
    int idx = blockIdx.x * 256 + threadIdx.x;   // b*4096 + p
    int b = idx >> 12, p = idx & 4095;
    const float* qb = Q + (size_t)b * 64 * HW + p;
    const float* kb = K + (size_t)b * 64 * HW + p;
    float sq = 0.f, sk = 0.f;
#pragma unroll 8
    for (int c = 0; c < 64; ++c) {
        float a = qb[(size_t)c * HW];
        float d = kb[(size_t)c * HW];
        sq = fmaf(a, a, sq);
        sk = fmaf(d, d, sk);
    }
    pix2q[idx] = sq;
    pix2k[idx] = sk;
}

// ---------------- patch reciprocal norms: 1/max(sqrt(3x3 box sum), 1e-12) ----
__global__ void patchnorm_kernel(const float* __restrict__ pix2q, const float* __restrict__ pix2k,
                                 float* __restrict__ rnq, float* __restrict__ rnk) {
    int idx = blockIdx.x * 256 + threadIdx.x;   // b*4096 + p
    int b = idx >> 12, p = idx & 4095;
    int py = p >> 6, px = p & 63;
    float sq = 0.f, sk = 0.f;
    for (int dy = -1; dy <= 1; ++dy)
        for (int dx = -1; dx <= 1; ++dx) {
            int yy = py + dy, xx = px + dx;
            if ((unsigned)yy < 64u && (unsigned)xx < 64u) {
                int o = (b << 12) + (yy << 6) + xx;
                sq += pix2q[o];
                sk += pix2k[o];
            }
        }
    rnq[idx] = 1.f / fmaxf(sqrtf(sq), 1e-12f);
    rnk[idx] = 1.f / fmaxf(sqrtf(sk), 1e-12f);
}

// ---------------- fused GEMM + x-diagonal 3-sum (full D, one batch) ----------
// D[q][k] = sum_c Q[c][q]*K[c][k];  Dx[q][k] = D[q-1][k-1] + D[q][k] + D[q+1][k+1]
// with x-shift terms masked at image edges (qx/kx in {0,63}).
// Tile 128q x 128k, K=64. Micro-tile: q = q0 + iG*64 + ty*4 + i, k = k0 + jG*64 + tx*4 + j.
// Grid (32,32): 1024 WGs = exactly 2 occupancy rounds at 2 WG/CU. No q masks (full D).
__global__ __launch_bounds__(256, 2)
void gemm_dx_kernel(const float* __restrict__ Q, const float* __restrict__ K,
                    float* __restrict__ Dx, int b) {
    __shared__ __align__(16) float sdata[16384];   // As[64][128] | Bs[64][128]; epilogue: xch
    float* As = sdata;
    float* Bs = sdata + 8192;
    const int tid = threadIdx.x;
    const int tx = tid & 15, ty = tid >> 4;
    const int lane = tid & 63;
    const int k0 = blockIdx.x * 128;
    const int q0 = blockIdx.y * 128;
    const float* Qb = Q + (size_t)b * 64 * HW;
    const float* Kb = K + (size_t)b * 64 * HW;

#pragma unroll
    for (int t = 0; t < 8; ++t) {
        int i4 = t * 256 + tid;            // 0..2047 float4 slots
        int c = i4 >> 5;
        int col = (i4 & 31) * 4;
        *(float4*)&As[c * 128 + col] = *(const float4*)&Qb[(size_t)c * HW + q0 + col];
        *(float4*)&Bs[c * 128 + col] = *(const float4*)&Kb[(size_t)c * HW + k0 + col];
    }
    __syncthreads();

    float accf[8][8];                      // [r=iG*4+i][cc=jG*4+j]
#pragma unroll
    for (int r = 0; r < 8; ++r)
#pragma unroll
        for (int cc = 0; cc < 8; ++cc) accf[r][cc] = 0.f;

#pragma unroll 8
    for (int c = 0; c < 64; ++c) {
        float4 a0 = *(const float4*)&As[c * 128 + ty * 4];
        float4 a1 = *(const float4*)&As[c * 128 + 64 + ty * 4];
        float4 b0 = *(const float4*)&Bs[c * 128 + tx * 4];
        float4 b1 = *(const float4*)&Bs[c * 128 + 64 + tx * 4];
        float av[8] = {a0.x, a0.y, a0.z, a0.w, a1.x, a1.y, a1.z, a1.w};
        float bv[8] = {b0.x, b0.y, b0.z, b0.w, b1.x, b1.y, b1.z, b1.w};
#pragma unroll
        for (int r = 0; r < 8; ++r)
#pragma unroll
            for (int cc = 0; cc < 8; ++cc) accf[r][cc] = fmaf(av[r], bv[cc], accf[r][cc]);
    }
    __syncthreads();   // As/Bs dead; reuse front of sdata as exchange buffer

    // wave-boundary row exchange: rows qx in {15,31,47} (side0) and {16,32,48} (side1), per iG
    float* xch = sdata;
    bool wlow  = (ty == 3 || ty == 7 || ty == 11);    // writes its i=3 rows (qx 15/31/47)
    bool whigh = (ty == 4 || ty == 8 || ty == 12);    // writes its i=0 rows (qx 16/32/48)
    if (wlow) {
        int bnd = ty >> 2;
#pragma unroll
        for (int iG = 0; iG < 2; ++iG)
#pragma unroll
            for (int jG = 0; jG < 2; ++jG)
#pragma unroll
                for (int j = 0; j < 4; ++j)
                    xch[((iG * 3 + bnd) * 2 + 0) * 132 + jG * 64 + tx * 4 + j] = accf[iG * 4 + 3][jG * 4 + j];
    }
    if (whigh) {
        int bnd = (ty >> 2) - 1;
#pragma unroll
        for (int iG = 0; iG < 2; ++iG)
#pragma unroll
            for (int jG = 0; jG < 2; ++jG)
#pragma unroll
                for (int j = 0; j < 4; ++j)
                    xch[((iG * 3 + bnd) * 2 + 1) * 132 + jG * 64 + tx * 4 + j] = accf[iG * 4][jG * 4 + j];
    }
    __syncthreads();

    // cross-thread neighbor values via in-wave shuffles (garbage lanes masked later)
    float Lv[8][2], Rv[8][2], Uv[2][2][3], Dv[2][2][3], cUL[2][2], cDR[2][2];
#pragma unroll
    for (int m = 0; m < 7; ++m)
#pragma unroll
        for (int g = 0; g < 2; ++g) Lv[m][g] = __shfl(accf[m][g * 4 + 3], lane - 1, 64);
#pragma unroll
    for (int m = 1; m < 8; ++m)
#pragma unroll
        for (int g = 0; g < 2; ++g) Rv[m][g] = __shfl(accf[m][g * 4], lane + 1, 64);
#pragma unroll
    for (int iG = 0; iG < 2; ++iG)
#pragma unroll
        for (int g = 0; g < 2; ++g) {
#pragma unroll
            for (int m = 0; m < 3; ++m) {
                Uv[iG][g][m] = __shfl(accf[iG * 4 + 3][g * 4 + m], lane - 16, 64);
                Dv[iG][g][m] = __shfl(accf[iG * 4][g * 4 + m + 1], lane + 16, 64);
            }
            cUL[iG][g] = __shfl(accf[iG * 4 + 3][g * 4 + 3], lane - 17, 64);
            cDR[iG][g] = __shfl(accf[iG * 4][g * 4], lane + 17, 64);
        }
    if (whigh) {   // row above (qx0-1) comes from LDS (crosses wave)
        int bnd = (ty >> 2) - 1;
#pragma unroll
        for (int iG = 0; iG < 2; ++iG)
#pragma unroll
            for (int g = 0; g < 2; ++g) {
                int base = ((iG * 3 + bnd) * 2 + 0) * 132 + g * 64 + tx * 4;
#pragma unroll
                for (int m = 0; m < 3; ++m) Uv[iG][g][m] = xch[base + m];
                cUL[iG][g] = xch[base > 0 ? base - 1 : 0];
            }
    }
    if (wlow) {    // row below (qx0+4)
        int bnd = ty >> 2;
#pragma unroll
        for (int iG = 0; iG < 2; ++iG)
#pragma unroll
            for (int g = 0; g < 2; ++g) {
                int base = ((iG * 3 + bnd) * 2 + 1) * 132 + g * 64 + tx * 4;
#pragma unroll
                for (int m = 0; m < 3; ++m) Dv[iG][g][m] = xch[base + m + 1];
                cDR[iG][g] = xch[base + 4];
            }
    }

    // assemble Dx and store (row index = global q, single-batch buffer)
#pragma unroll
    for (int r = 0; r < 8; ++r) {
        int iG = r >> 2, i3 = r & 3;
        size_t row = (size_t)(q0 + iG * 64 + ty * 4 + i3);
#pragma unroll
        for (int jG = 0; jG < 2; ++jG) {
            float o[4];
#pragma unroll
            for (int j3 = 0; j3 < 4; ++j3) {
                int cc = jG * 4 + j3;
                float dm, dp;
                if (i3 > 0) dm = (j3 > 0) ? accf[r - 1][cc - 1] : Lv[r - 1][jG];
                else        dm = (j3 > 0) ? Uv[iG][jG][j3 - 1] : cUL[iG][jG];
                if (i3 < 3) dp = (j3 < 3) ? accf[r + 1][cc + 1] : Rv[r + 1][jG];
                else        dp = (j3 < 3) ? Dv[iG][jG][j3] : cDR[iG][jG];
                int qx = ty * 4 + i3, kx = tx * 4 + j3;
                float v = accf[r][cc];
                if (qx > 0 && kx > 0)   v += dm;
                if (qx < 63 && kx < 63) v += dp;
                o[j3] = v;
            }
            *(float4*)&Dx[row * HW + k0 + jG * 64 + tx * 4] = make_float4(o[0], o[1], o[2], o[3]);
        }
    }
}

// ---------------- reduce: y-diagonal 3-sum + argmax, pure-register pipeline ---
// R[(qy,qx)][(ky,kx)] = Dx[qy-1][ky-1] + Dx[qy][ky] + Dx[qy+1][ky+1] (same qx,kx)
// thread: (wq -> qx, lane -> kx); grid (s, qxT, qyb): qy = 8*qyb + j, ky split s.
__global__ __launch_bounds__(256, 4)
void reduce_kernel(const float* __restrict__ Dx, const float* __restrict__ rnkA,
                   float* __restrict__ part_val, int* __restrict__ part_arg, int b) {
    const int s = blockIdx.x;          // 0..7
    const int qxT = blockIdx.y;        // 0..15
    const int qyb = blockIdx.z;        // 0..7
    const int tid = threadIdx.x;
    const int kx = tid & 63, wq = tid >> 6;
    const int qx = qxT * 4 + wq;
    const int qy0 = qyb * 8;

    float P0[8], P1[8], best[8];
    int barg[8];
#pragma unroll
    for (int j = 0; j < 8; ++j) { P0[j] = 0.f; P1[j] = 0.f; best[j] = -INFINITY; barg[j] = 0; }

    const int t0 = s * 8 - 1;
    for (int step = 0; step < 10; ++step) {
        int t = t0 + step;
        bool tval = (unsigned)t < 64u;
        float E[10];
#pragma unroll
        for (int lj = 0; lj < 10; ++lj) {
            int qy = qy0 - 1 + lj;
            bool v = tval && (unsigned)qy < 64u;
            E[lj] = v ? Dx[(size_t)((qy << 6) + qx) * HW + t * 64 + kx] : 0.f;
        }
        if (step >= 2) {
            float rk = rnkA[(b << 12) + ((t - 1) << 6) + kx];   // key = (t-1, kx), always valid
            int kg = (t - 1) * 64 + kx;
#pragma unroll
            for (int j = 0; j < 8; ++j) {
                float v = (P1[j] + E[j + 2]) * rk;
                if (v > best[j]) { best[j] = v; barg[j] = kg; }   // strict >: first max wins
            }
        }
#pragma unroll
        for (int j = 0; j < 8; ++j) { P1[j] = P0[j] + E[j + 1]; P0[j] = E[j]; }
    }

#pragma unroll
    for (int j = 0; j < 8; ++j) {
        float v = best[j];
        int a = barg[j];
#pragma unroll
        for (int m = 32; m >= 1; m >>= 1) {
            float ov = __shfl_xor(v, m, 64);
            int oa = __shfl_xor(a, m, 64);
            if (ov > v || (ov == v && oa < a)) { v = ov; a = oa; }
        }
        if (kx == 0) {
            int qy = qy0 + j;
            int pi = ((b << 12) + (qy << 6) + qx) * 8 + s;
            part_val[pi] = v;
            part_arg[pi] = a;
        }
    }
}

// ---------------- combine k-split partials, apply 1/||Q patch||, emit S + arg --
__global__ void combine_kernel(const float* __restrict__ part_val, const int* __restrict__ part_arg,
                               const float* __restrict__ rnqA,
                               float* __restrict__ S_out, int* __restrict__ arg_out) {
    int idx = blockIdx.x * 256 + threadIdx.x;   // b*4096 + q
    const float* pv = part_val + (size_t)idx * 8;
    const int* pa = part_arg + (size_t)idx * 8;
    float bv = -INFINITY;
    int ba = 0;
#pragma unroll
    for (int s = 0; s < 8; ++s) {   // ascending s = ascending k ranges: first max wins
        float v = pv[s];
        int a = pa[s];
        if (v > bv) { bv = v; ba = a; }
    }
    S_out[idx] = bv * rnqA[idx];
    arg_out[idx] = ba;
}

// ---------------- gather + fold: T[c,y,x] = (1/9) sum_{dy,dx} Vzp[c, a(q)+d], q=(y-dy,x-dx)
__global__ __launch_bounds__(256)
void gather_kernel(const float* __restrict__ V, const int* __restrict__ arg,
                   float* __restrict__ T_out) {
    int y = blockIdx.x, b = blockIdx.y;
    int tid = threadIdx.x;
    int x = tid & 63, cq = tid >> 6;
    int off[9];
#pragma unroll
    for (int t = 0; t < 9; ++t) {
        int dy = t / 3 - 1, dx = t % 3 - 1;
        int qy = y - dy, qx = x - dx;
        int o = -1;
        if ((unsigned)qy < 64u && (unsigned)qx < 64u) {
            int a = arg[(b << 12) + (qy << 6) + qx];
            int sy = (a >> 6) + dy, sx = (a & 63) + dx;
            if ((unsigned)sy < 64u && (unsigned)sx < 64u) o = (sy << 6) + sx;
        }
        off[t] = o;
    }
    const float* Vb = V + (size_t)b * 64 * HW;
    float* Tb = T_out + (size_t)b * 64 * HW + (y << 6) + x;
    for (int ci = 0; ci < 16; ++ci) {
        int c = cq * 16 + ci;
        const float* Vc = Vb + (size_t)c * HW;
        float acc = 0.f;
#pragma unroll
        for (int t = 0; t < 9; ++t)
            acc += (off[t] >= 0) ? Vc[off[t]] : 0.f;
        Tb[(size_t)c * HW] = acc * (1.f / 9.f);
    }
}

extern "C" void kernel_launch(void* const* d_in, const int* in_sizes, int n_in,
                              void* d_out, int out_size, void* d_ws, size_t ws_size,
                              hipStream_t stream) {
    const float* V = (const float*)d_in[0];
    const float* K = (const float*)d_in[1];
    const float* Q = (const float*)d_in[2];
    float* S_out = (float*)d_out;            // 4*4096
    float* T_out = S_out + 4 * HW;           // 4*64*4096

    char* ws = (char*)d_ws;
    float* pix2q = (float*)ws;               // 16384 f
    float* pix2k = pix2q + 16384;
    float* rnq = pix2k + 16384;
    float* rnk = rnq + 16384;
    int* argb = (int*)(rnk + 16384);
    float* part_val = (float*)(argb + 16384);        // 4*4096*8 f
    int* part_arg = (int*)(part_val + 131072);
    float* Dx = (float*)(ws + 1376256);      // single-batch full D: 4096*4096*4 = 64 MiB,
                                             // reused for all 4 batches -> stays L3-resident

    pixnorm_kernel<<<64, 256, 0, stream>>>(Q, K, pix2q, pix2k);
    patchnorm_kernel<<<64, 256, 0, stream>>>(pix2q, pix2k, rnq, rnk);
    for (int b = 0; b < 4; ++b) {
        gemm_dx_kernel<<<dim3(32, 32), 256, 0, stream>>>(Q, K, Dx, b);
        reduce_kernel<<<dim3(8, 16, 8), 256, 0, stream>>>(Dx, rnk, part_val, part_arg, b);
    }
    combine_kernel<<<64, 256, 0, stream>>>(part_val, part_arg, rnq, S_out, argb);
    gather_kernel<<<dim3(64, 4), 256, 0, stream>>>(V, argb, T_out);
}

// Round 4
// 297.052 us; speedup vs baseline: 2.4508x; 1.1748x over previous
//
#include <hip/hip_runtime.h>
#include <math.h>

#define HW 4096   // H*W = 64*64; B=4, C=64, H=W=64, L=4096

typedef short bf16x8 __attribute__((ext_vector_type(8)));
typedef float floatx4 __attribute__((ext_vector_type(4)));

__device__ __forceinline__ unsigned short f2bf_rne(float x) {
    unsigned int u = __float_as_uint(x);
    unsigned int r = (u + 0x7FFFu + ((u >> 16) & 1u)) >> 16;
    return (unsigned short)r;
}
__device__ __forceinline__ float bf2f(unsigned short h) {
    return __uint_as_float(((unsigned int)h) << 16);
}

// ---------------- pixel squared norms (per-pixel, over C) ----------------
__global__ void pixnorm_kernel(const float* __restrict__ Q, const float* __restrict__ K,
                               float* __restrict__ pix2q, float* __restrict__ pix2k) {
    int idx = blockIdx.x * 256 + threadIdx.x;   // b*4096 + p
    int b = idx >> 12, p = idx & 4095;
    const float* qb = Q + (size_t)b * 64 * HW + p;
    const float* kb = K + (size_t)b * 64 * HW + p;
    float sq = 0.f, sk = 0.f;
#pragma unroll 8
    for (int c = 0; c < 64; ++c) {
        float a = qb[(size_t)c * HW];
        float d = kb[(size_t)c * HW];
        sq = fmaf(a, a, sq);
        sk = fmaf(d, d, sk);
    }
    pix2q[idx] = sq;
    pix2k[idx] = sk;
}

// ---------------- patch reciprocal norms: 1/max(sqrt(3x3 box sum), 1e-12) ----
__global__ void patchnorm_kernel(const float* __restrict__ pix2q, const float* __restrict__ pix2k,
                                 float* __restrict__ rnq, float* __restrict__ rnk) {
    int idx = blockIdx.x * 256 + threadIdx.x;   // b*4096 + p
    int b = idx >> 12, p = idx & 4095;
    int py = p >> 6, px = p & 63;
    float sq = 0.f, sk = 0.f;
    for (int dy = -1; dy <= 1; ++dy)
        for (int dx = -1; dx <= 1; ++dx) {
            int yy = py + dy, xx = px + dx;
            if ((unsigned)yy < 64u && (unsigned)xx < 64u) {
                int o = (b << 12) + (yy << 6) + xx;
                sq += pix2q[o];
                sk += pix2k[o];
            }
        }
    rnq[idx] = 1.f / fmaxf(sqrtf(sq), 1e-12f);
    rnk[idx] = 1.f / fmaxf(sqrtf(sk), 1e-12f);
}

// ---------------- prep: split fp32 -> bf16 (hi,lo), transpose to [p][c] ------
// Aq[b][p][0:64]=Qh, [64:128]=Qh, [128:192]=Ql   (A' = [Qh;Qh;Ql])
// Bq[b][p][0:64]=Kh, [64:128]=Kl, [128:192]=Kh   (B' = [Kh;Kl;Kh])
// so sum over c'=0..191 of A'[c'][q] B'[c'][k] = QhKh + QhKl + QlKh ~= fp32 dot.
__global__ __launch_bounds__(256)
void prep_kernel(const float* __restrict__ Q, const float* __restrict__ K,
                 unsigned short* __restrict__ Aq, unsigned short* __restrict__ Bq) {
    __shared__ float sT[64][65];
    const int tid = threadIdx.x;
    const int p0 = blockIdx.x * 64;
    const int b = blockIdx.y;
    const int pp = tid >> 2, qt = tid & 3;
    const size_t base = ((size_t)b * 4096 + p0 + pp) * 192;

    // ---- Q -> Aq ----
#pragma unroll
    for (int it = 0; it < 16; ++it) {
        int idx = it * 256 + tid;
        int c = idx >> 6, x = idx & 63;
        sT[c][x] = Q[((size_t)b * 64 + c) * HW + p0 + x];
    }
    __syncthreads();
#pragma unroll
    for (int i = 0; i < 16; ++i) {
        int c = qt * 16 + i;
        float x = sT[c][pp];
        unsigned short h = f2bf_rne(x);
        unsigned short l = f2bf_rne(x - bf2f(h));
        Aq[base + c] = h;
        Aq[base + 64 + c] = h;
        Aq[base + 128 + c] = l;
    }
    __syncthreads();

    // ---- K -> Bq ----
#pragma unroll
    for (int it = 0; it < 16; ++it) {
        int idx = it * 256 + tid;
        int c = idx >> 6, x = idx & 63;
        sT[c][x] = K[((size_t)b * 64 + c) * HW + p0 + x];
    }
    __syncthreads();
#pragma unroll
    for (int i = 0; i < 16; ++i) {
        int c = qt * 16 + i;
        float x = sT[c][pp];
        unsigned short h = f2bf_rne(x);
        unsigned short l = f2bf_rne(x - bf2f(h));
        Bq[base + c] = h;
        Bq[base + 64 + c] = l;
        Bq[base + 128 + c] = h;
    }
}

// ---------------- MFMA GEMM (K=192 split-bf16) + fused x-diagonal 3-sum ------
// Dx[q][k] = D[q][k] + D[q-1][k-1]*(qx>0&kx>0) + D[q+1][k+1]*(qx<63&kx<63)
// Tile 128x128; 4 waves, each a 64x64 quadrant of 4x4 16x16x32 MFMAs.
// LDS: staged A/B panels (XOR-granule swizzle), reused as Csh[128][132] in epilogue.
__global__ __launch_bounds__(256, 2)
void gemm_mfma_kernel(const unsigned short* __restrict__ Aq, const unsigned short* __restrict__ Bq,
                      float* __restrict__ Dx, int b) {
    __shared__ __align__(16) char smem[128 * 132 * 4];   // 67584 B >= 2*16384 staging
    const int tid = threadIdx.x;
    const int lane = tid & 63, wid = tid >> 6;
    const int m15 = lane & 15, quad = lane >> 4;
    const int wm = wid & 1, wn = wid >> 1;
    const int k0 = blockIdx.x * 128;
    const int q0 = blockIdx.y * 128;
    const unsigned short* Aqb = Aq + (size_t)b * 4096 * 192;
    const unsigned short* Bqb = Bq + (size_t)b * 4096 * 192;

    floatx4 acc[4][4];
#pragma unroll
    for (int i = 0; i < 4; ++i)
#pragma unroll
        for (int j = 0; j < 4; ++j) acc[i][j] = (floatx4)0.f;

    for (int s = 0; s < 3; ++s) {
        const int cbase = s * 64;
        // stage As[128 rows][8 granules] and Bs likewise; granule g of row r sits at
        // position g^(r&7) -> fragment reads are 2-way bank aliased (free).
#pragma unroll
        for (int it = 0; it < 4; ++it) {
            int slot = it * 256 + tid;
            int row = slot >> 3, pos = slot & 7;
            int G = pos ^ (row & 7);
            uint4 va = *(const uint4*)(Aqb + ((size_t)(q0 + row)) * 192 + cbase + G * 8);
            uint4 vb = *(const uint4*)(Bqb + ((size_t)(k0 + row)) * 192 + cbase + G * 8);
            *(uint4*)(smem + slot * 16) = va;
            *(uint4*)(smem + 16384 + slot * 16) = vb;
        }
        __syncthreads();
#pragma unroll
        for (int kk = 0; kk < 2; ++kk) {
            bf16x8 af[4], bfr[4];
#pragma unroll
            for (int mt = 0; mt < 4; ++mt) {
                int row = wm * 64 + mt * 16 + m15;
                int pos = (kk * 4 + quad) ^ (row & 7);
                af[mt] = *(const bf16x8*)(smem + (row * 8 + pos) * 16);
            }
#pragma unroll
            for (int nt = 0; nt < 4; ++nt) {
                int row = wn * 64 + nt * 16 + m15;
                int pos = (kk * 4 + quad) ^ (row & 7);
                bfr[nt] = *(const bf16x8*)(smem + 16384 + (row * 8 + pos) * 16);
            }
#pragma unroll
            for (int mt = 0; mt < 4; ++mt)
#pragma unroll
                for (int nt = 0; nt < 4; ++nt)
                    acc[mt][nt] = __builtin_amdgcn_mfma_f32_16x16x32_bf16(
                        af[mt], bfr[nt], acc[mt][nt], 0, 0, 0);
        }
        __syncthreads();
    }

    // ---- epilogue: C tile -> LDS (stride 132), x-diag 3-sum, store Dx ----
    float* Csh = (float*)smem;
#pragma unroll
    for (int mt = 0; mt < 4; ++mt)
#pragma unroll
        for (int nt = 0; nt < 4; ++nt)
#pragma unroll
            for (int j = 0; j < 4; ++j)
                Csh[(wm * 64 + mt * 16 + quad * 4 + j) * 132 + wn * 64 + nt * 16 + m15] =
                    acc[mt][nt][j];
    __syncthreads();

    const int q_l = tid >> 1;
    const int cb = (tid & 1) * 64;
    const bool qm = (q_l & 63) > 0;      // diag- allowed in q (qx>0)
    const bool qp = (q_l & 63) < 63;     // diag+ allowed in q (qx<63)
    float4 prevm = make_float4(0.f, 0.f, 0.f, 0.f);
    float4 rpj   = qp ? *(const float4*)&Csh[(q_l + 1) * 132 + cb] : make_float4(0.f, 0.f, 0.f, 0.f);
    float* dst = Dx + (size_t)(q0 + q_l) * HW + k0 + cb;
#pragma unroll
    for (int j = 0; j < 16; ++j) {
        int c = cb + 4 * j;
        float4 cen = *(const float4*)&Csh[q_l * 132 + c];
        float4 rm  = qm ? *(const float4*)&Csh[(q_l - 1) * 132 + c] : make_float4(0.f, 0.f, 0.f, 0.f);
        float4 rp1 = (qp && j < 15) ? *(const float4*)&Csh[(q_l + 1) * 132 + c + 4]
                                    : make_float4(0.f, 0.f, 0.f, 0.f);
        float4 o;
        o.x = cen.x + prevm.w + rpj.y;
        o.y = cen.y + rm.x    + rpj.z;
        o.z = cen.z + rm.y    + rpj.w;
        o.w = cen.w + rm.z    + rp1.x;
        if (j == 0)  o.x = cen.x + rpj.y;   // kx==0: no diag-
        if (j == 15) o.w = cen.w + rm.z;    // kx==63: no diag+
        *(float4*)(dst + 4 * j) = o;
        prevm = rm;
        rpj = rp1;
    }
}

// ---------------- reduce: y-diagonal 3-sum + argmax, pure-register pipeline ---
// R[(qy,qx)][(ky,kx)] = Dx[qy-1][ky-1] + Dx[qy][ky] + Dx[qy+1][ky+1] (same qx,kx)
__global__ __launch_bounds__(256, 4)
void reduce_kernel(const float* __restrict__ Dx, const float* __restrict__ rnkA,
                   float* __restrict__ part_val, int* __restrict__ part_arg, int b) {
    const int s = blockIdx.x;          // 0..7
    const int qxT = blockIdx.y;        // 0..15
    const int qyb = blockIdx.z;        // 0..7
    const int tid = threadIdx.x;
    const int kx = tid & 63, wq = tid >> 6;
    const int qx = qxT * 4 + wq;
    const int qy0 = qyb * 8;

    float P0[8], P1[8], best[8];
    int barg[8];
#pragma unroll
    for (int j = 0; j < 8; ++j) { P0[j] = 0.f; P1[j] = 0.f; best[j] = -INFINITY; barg[j] = 0; }

    const int t0 = s * 8 - 1;
    for (int step = 0; step < 10; ++step) {
        int t = t0 + step;
        bool tval = (unsigned)t < 64u;
        float E[10];
#pragma unroll
        for (int lj = 0; lj < 10; ++lj) {
            int qy = qy0 - 1 + lj;
            bool v = tval && (unsigned)qy < 64u;
            E[lj] = v ? Dx[(size_t)((qy << 6) + qx) * HW + t * 64 + kx] : 0.f;
        }
        if (step >= 2) {
            float rk = rnkA[(b << 12) + ((t - 1) << 6) + kx];   // key = (t-1, kx)
            int kg = (t - 1) * 64 + kx;
#pragma unroll
            for (int j = 0; j < 8; ++j) {
                float v = (P1[j] + E[j + 2]) * rk;
                if (v > best[j]) { best[j] = v; barg[j] = kg; }   // strict >: first max wins
            }
        }
#pragma unroll
        for (int j = 0; j < 8; ++j) { P1[j] = P0[j] + E[j + 1]; P0[j] = E[j]; }
    }

#pragma unroll
    for (int j = 0; j < 8; ++j) {
        float v = best[j];
        int a = barg[j];
#pragma unroll
        for (int m = 32; m >= 1; m >>= 1) {
            float ov = __shfl_xor(v, m, 64);
            int oa = __shfl_xor(a, m, 64);
            if (ov > v || (ov == v && oa < a)) { v = ov; a = oa; }
        }
        if (kx == 0) {
            int qy = qy0 + j;
            int pi = ((b << 12) + (qy << 6) + qx) * 8 + s;
            part_val[pi] = v;
            part_arg[pi] = a;
        }
    }
}

// ---------------- combine k-split partials, apply 1/||Q patch||, emit S + arg --
__global__ void combine_kernel(const float* __restrict__ part_val, const int* __restrict__ part_arg,
                               const float* __restrict__ rnqA,
                               float* __restrict__ S_out, int* __restrict__ arg_out) {
    int idx = blockIdx.x * 256 + threadIdx.x;   // b*4096 + q
    const float* pv = part_val + (size_t)idx * 8;
    const int* pa = part_arg + (size_t)idx * 8;
    float bv = -INFINITY;
    int ba = 0;
#pragma unroll
    for (int s = 0; s < 8; ++s) {   // ascending s = ascending k ranges: first max wins
        float v = pv[s];
        int a = pa[s];
        if (v > bv) { bv = v; ba = a; }
    }
    S_out[idx] = bv * rnqA[idx];
    arg_out[idx] = ba;
}

// ---------------- gather + fold: T[c,y,x] = (1/9) sum_{dy,dx} Vzp[c, a(q)+d], q=(y-dy,x-dx)
__global__ __launch_bounds__(256)
void gather_kernel(const float* __restrict__ V, const int* __restrict__ arg,
                   float* __restrict__ T_out) {
    int y = blockIdx.x, b = blockIdx.y;
    int tid = threadIdx.x;
    int x = tid & 63, cq = tid >> 6;
    int off[9];
#pragma unroll
    for (int t = 0; t < 9; ++t) {
        int dy = t / 3 - 1, dx = t % 3 - 1;
        int qy = y - dy, qx = x - dx;
        int o = -1;
        if ((unsigned)qy < 64u && (unsigned)qx < 64u) {
            int a = arg[(b << 12) + (qy << 6) + qx];
            int sy = (a >> 6) + dy, sx = (a & 63) + dx;
            if ((unsigned)sy < 64u && (unsigned)sx < 64u) o = (sy << 6) + sx;
        }
        off[t] = o;
    }
    const float* Vb = V + (size_t)b * 64 * HW;
    float* Tb = T_out + (size_t)b * 64 * HW + (y << 6) + x;
    for (int ci = 0; ci < 16; ++ci) {
        int c = cq * 16 + ci;
        const float* Vc = Vb + (size_t)c * HW;
        float acc = 0.f;
#pragma unroll
        for (int t = 0; t < 9; ++t)
            acc += (off[t] >= 0) ? Vc[off[t]] : 0.f;
        Tb[(size_t)c * HW] = acc * (1.f / 9.f);
    }
}

extern "C" void kernel_launch(void* const* d_in, const int* in_sizes, int n_in,
                              void* d_out, int out_size, void* d_ws, size_t ws_size,
                              hipStream_t stream) {
    const float* V = (const float*)d_in[0];
    const float* K = (const float*)d_in[1];
    const float* Q = (const float*)d_in[2];
    float* S_out = (float*)d_out;            // 4*4096
    float* T_out = S_out + 4 * HW;           // 4*64*4096

    char* ws = (char*)d_ws;
    float* pix2q = (float*)ws;               // 16384 f
    float* pix2k = pix2q + 16384;
    float* rnq = pix2k + 16384;
    float* rnk = rnq + 16384;
    int* argb = (int*)(rnk + 16384);
    float* part_val = (float*)(argb + 16384);        // 4*4096*8 f
    int* part_arg = (int*)(part_val + 131072);
    float* Dx = (float*)(ws + 1376256);              // 64 MiB, reused across batches
    unsigned short* Aq = (unsigned short*)(ws + 68485120);   // 4*4096*192 bf16 = 6 MiB
    unsigned short* Bq = (unsigned short*)(ws + 74776576);   // 6 MiB

    prep_kernel<<<dim3(64, 4), 256, 0, stream>>>(Q, K, Aq, Bq);
    pixnorm_kernel<<<64, 256, 0, stream>>>(Q, K, pix2q, pix2k);
    patchnorm_kernel<<<64, 256, 0, stream>>>(pix2q, pix2k, rnq, rnk);
    for (int b = 0; b < 4; ++b) {
        gemm_mfma_kernel<<<dim3(32, 32), 256, 0, stream>>>(Aq, Bq, Dx, b);
        reduce_kernel<<<dim3(8, 16, 8), 256, 0, stream>>>(Dx, rnk, part_val, part_arg, b);
    }
    combine_kernel<<<64, 256, 0, stream>>>(part_val, part_arg, rnq, S_out, argb);
    gather_kernel<<<dim3(64, 4), 256, 0, stream>>>(V, argb, T_out);
}